// Round 11
// baseline (600.038 us; speedup 1.0000x reference)
//
#include <hip/hip_runtime.h>
#include <hip/hip_bf16.h>

typedef __attribute__((ext_vector_type(8)))  __bf16         bf16x8;
typedef __attribute__((ext_vector_type(4)))  float          f32x4;

#define LOG2E 1.44269504088896340736f

#if __has_builtin(__builtin_amdgcn_exp2f)
#define EXP2F(x) __builtin_amdgcn_exp2f(x)
#else
#define EXP2F(x) __builtin_exp2f(x)
#endif

__device__ __forceinline__ unsigned short f2b(float f) {
  union { __bf16 h; unsigned short s; } o; o.h = (__bf16)f; return o.s;
}

// ---------------- kernel 1: h = x@W fp32 (VALU); hT bf16, s1', s2' ----------
// UNCHANGED from green rounds 8/10.
__global__ __launch_bounds__(256) void k_prep(
    const float* __restrict__ x, const float* __restrict__ W,
    const float* __restrict__ a1, const float* __restrict__ a2,
    const float* __restrict__ ab,
    unsigned short* __restrict__ hT, float* __restrict__ s1p,
    float* __restrict__ s2p) {
  __shared__ __align__(16) float Ws[64 * 128];
  __shared__ __align__(16) float Xs[16 * 128];
  const int t = threadIdx.x;
  const int rb = blockIdx.x * 16;
  const int r  = t >> 4;
  const int fg = t & 15;

  {
    int off = t * 8;
    *(f32x4*)(Xs + off)     = *(const f32x4*)(x + (long)rb * 128 + off);
    *(f32x4*)(Xs + off + 4) = *(const f32x4*)(x + (long)rb * 128 + off + 4);
  }

  float acc[8];
#pragma unroll
  for (int j = 0; j < 8; ++j) acc[j] = 0.f;

  for (int half = 0; half < 2; ++half) {
    __syncthreads();
#pragma unroll
    for (int c = 0; c < 8; ++c) {
      int off = c * 1024 + t * 4;
      *(f32x4*)(Ws + off) = *(const f32x4*)(W + half * 8192 + off);
    }
    __syncthreads();
    for (int k = 0; k < 64; ++k) {
      float xv = Xs[r * 128 + half * 64 + k];
      f32x4 w0 = *(const f32x4*)(Ws + k * 128 + fg * 8);
      f32x4 w1 = *(const f32x4*)(Ws + k * 128 + fg * 8 + 4);
#pragma unroll
      for (int j = 0; j < 4; ++j) {
        acc[j]     += xv * w0[j];
        acc[4 + j] += xv * w1[j];
      }
    }
  }

  float p1 = 0.f, p2 = 0.f;
#pragma unroll
  for (int j = 0; j < 8; ++j) {
    p1 += acc[j] * a1[fg * 8 + j];
    p2 += acc[j] * a2[fg * 8 + j];
  }
#pragma unroll
  for (int mask = 1; mask <= 8; mask <<= 1) {
    p1 += __shfl_xor(p1, mask, 64);
    p2 += __shfl_xor(p2, mask, 64);
  }
  if (fg == 0) {
    s1p[rb + r] = LOG2E * (p1 + ab[0]);
    s2p[rb + r] = LOG2E * p2;
  }
#pragma unroll
  for (int j = 0; j < 8; ++j)
    hT[(long)(fg * 8 + j) * 8192 + rb + r] = f2b(acc[j]);
}

// ---------------- kernel 2 v4: barrier-free K-loop ---------------------------
// grid 512 x 128 thr (2 waves). Block = 16 rows; wave wv owns K-half wv.
// Key identity: lane (m=lane&15, quad=lane>>4) computing w for
// [row m][cols quad*8+j] IS the MFMA A-fragment layout -> w packs to bf16
// in-register (no As LDS). B-fragments load directly from L2-resident hT
// (16B contiguous per lane, 16 full cachelines per instruction). Zero
// __syncthreads in the K-loop; one LDS combine of the two K-halves at end.
__global__ __launch_bounds__(128) void k_attn(
    const float* __restrict__ adj, const unsigned short* __restrict__ hT,
    const float* __restrict__ s1p, const float* __restrict__ s2p,
    float* __restrict__ out) {
  __shared__ float accL[16 * 128];   // 8 KB: K-half-1 numerator
  __shared__ float denL[16];

  const int t = threadIdx.x;
  const int i0 = blockIdx.x * 16;
  const int lane = t & 63;
  const int wv = t >> 6;           // K-half 0/1
  const int m    = lane & 15;      // row within block / B col
  const int quad = lane >> 4;      // k-subgroup
  const long kbase = (long)wv * 4096;

  const float s1v = s1p[i0 + m];
  const float* adjp = adj + (long)(i0 + m) * 8192 + kbase + quad * 8;
  const float* s2pp = s2p + kbase + quad * 8;
  const unsigned short* hTq = hT + kbase + quad * 8;

  f32x4 acc[8];
#pragma unroll
  for (int ft = 0; ft < 8; ++ft)
#pragma unroll
    for (int p = 0; p < 4; ++p) acc[ft][p] = 0.f;
  float den = 0.f;

  // prologue: iter-0 adj (the HBM-latency stream; NT keeps hT hot in L2)
  f32x4 ca[4][2];
#pragma unroll
  for (int ks = 0; ks < 4; ++ks) {
    ca[ks][0] = __builtin_nontemporal_load((const f32x4*)(adjp + ks * 32));
    ca[ks][1] = __builtin_nontemporal_load((const f32x4*)(adjp + ks * 32 + 4));
  }

  for (int it = 0; it < 32; ++it) {
    // ---- prefetch next iter's adj (covered by w-compute + MFMA below) ----
    f32x4 na[4][2];
    if (it < 31) {
      const float* ap = adjp + (long)(it + 1) * 128;
#pragma unroll
      for (int ks = 0; ks < 4; ++ks) {
        na[ks][0] = __builtin_nontemporal_load((const f32x4*)(ap + ks * 32));
        na[ks][1] = __builtin_nontemporal_load((const f32x4*)(ap + ks * 32 + 4));
      }
    }

    // ---- w = adj * exp2(leaky(s1'+s2')) packed straight into A-frags ----
    bf16x8 afr[4];
#pragma unroll
    for (int ks = 0; ks < 4; ++ks) {
      const float* sp = s2pp + (long)it * 128 + ks * 32;
      f32x4 sv0 = *(const f32x4*)(sp);
      f32x4 sv1 = *(const f32x4*)(sp + 4);
#pragma unroll
      for (int j = 0; j < 4; ++j) {
        float tp0 = s1v + sv0[j];
        float w0 = ca[ks][0][j] * EXP2F(fmaxf(tp0, 0.2f * tp0));
        den += w0;
        afr[ks][j] = (__bf16)w0;
        float tp1 = s1v + sv1[j];
        float w1 = ca[ks][1][j] * EXP2F(fmaxf(tp1, 0.2f * tp1));
        den += w1;
        afr[ks][4 + j] = (__bf16)w1;
      }
    }

    // ---- B direct from hT (L2) + 32x mfma_f32_16x16x32_bf16 ----
    const unsigned short* hb = hTq + (long)it * 128;
#pragma unroll
    for (int ks = 0; ks < 4; ++ks) {
#pragma unroll
      for (int ft = 0; ft < 8; ++ft) {
        bf16x8 bv = *(const bf16x8*)(hb + (long)(ft * 16 + m) * 8192 + ks * 32);
        acc[ft] = __builtin_amdgcn_mfma_f32_16x16x32_bf16(afr[ks], bv, acc[ft], 0, 0, 0);
      }
    }

#pragma unroll
    for (int ks = 0; ks < 4; ++ks) { ca[ks][0] = na[ks][0]; ca[ks][1] = na[ks][1]; }
  }

  // ---- den: reduce over quads (lane bits 4,5); every lane holds row m's half ----
  den += __shfl_xor(den, 16, 64);
  den += __shfl_xor(den, 32, 64);

  // ---- combine K-halves via LDS (single barrier), divide, store ----
  if (wv == 1) {
    if (lane < 16) denL[lane] = den;
#pragma unroll
    for (int ft = 0; ft < 8; ++ft)
#pragma unroll
      for (int p = 0; p < 4; ++p)
        accL[(quad * 4 + p) * 128 + ft * 16 + m] = acc[ft][p];
  }
  __syncthreads();
  if (wv == 0) {
    float dtot = den + denL[m];   // total den for row m (this lane's row)
#pragma unroll
    for (int p = 0; p < 4; ++p) {
      int row = quad * 4 + p;     // C layout: col=m, row=quad*4+p [m89]
      float dr = __shfl(dtot, (lane & 0x30) | row, 64);
      float inv = (dr != 0.f) ? (1.f / dr) : 0.f;
#pragma unroll
      for (int ft = 0; ft < 8; ++ft) {
        float v = acc[ft][p] + accL[row * 128 + ft * 16 + m];
        out[(long)(i0 + row) * 128 + ft * 16 + m] = v * inv;
      }
    }
  }
}

extern "C" void kernel_launch(void* const* d_in, const int* in_sizes, int n_in,
                              void* d_out, int out_size, void* d_ws, size_t ws_size,
                              hipStream_t stream) {
  int ix = 0, iadj = 1, iw = 2, ia1 = 3, ia2 = 4, iab = 5;
  {
    int f128[2] = {-1, -1};
    int tx = -1, tadj = -1, tw = -1, tab = -1, n128 = 0;
    for (int i = 0; i < n_in; ++i) {
      int s = in_sizes[i];
      if (s == 67108864) tadj = i;
      else if (s == 1048576) tx = i;
      else if (s == 16384) tw = i;
      else if (s == 128 && n128 < 2) f128[n128++] = i;
      else if (s == 1) tab = i;
    }
    if (tx >= 0 && tadj >= 0 && tw >= 0 && tab >= 0 && n128 == 2) {
      ix = tx; iadj = tadj; iw = tw; ia1 = f128[0]; ia2 = f128[1]; iab = tab;
    }
  }
  const float* x   = (const float*)d_in[ix];
  const float* adj = (const float*)d_in[iadj];
  const float* W   = (const float*)d_in[iw];
  const float* a1  = (const float*)d_in[ia1];
  const float* a2  = (const float*)d_in[ia2];
  const float* ab  = (const float*)d_in[iab];

  char* ws = (char*)d_ws;
  unsigned short* hT = (unsigned short*)(ws);           // 2 MB  bf16 h^T [128][8192]
  float* s1p = (float*)(ws + 2097152);                  // 32 KB
  float* s2p = (float*)(ws + 2097152 + 32768);          // 32 KB

  k_prep<<<dim3(512), dim3(256), 0, stream>>>(x, W, a1, a2, ab, hT, s1p, s2p);
  k_attn<<<dim3(512), dim3(128), 0, stream>>>(adj, hT, s1p, s2p, (float*)d_out);
}

// Round 12
// 466.951 us; speedup vs baseline: 1.2850x; 1.2850x over previous
//
#include <hip/hip_runtime.h>
#include <hip/hip_bf16.h>

typedef __attribute__((ext_vector_type(8)))  __bf16         bf16x8;
typedef __attribute__((ext_vector_type(4)))  float          f32x4;

#define LOG2E 1.44269504088896340736f

#if __has_builtin(__builtin_amdgcn_exp2f)
#define EXP2F(x) __builtin_amdgcn_exp2f(x)
#else
#define EXP2F(x) __builtin_exp2f(x)
#endif

__device__ __forceinline__ unsigned short f2b(float f) {
  union { __bf16 h; unsigned short s; } o; o.h = (__bf16)f; return o.s;
}

// ---------------- kernel 1: h = x@W fp32 (VALU); hT bf16, s1', s2' ----------
// UNCHANGED from green rounds 8/10.
__global__ __launch_bounds__(256) void k_prep(
    const float* __restrict__ x, const float* __restrict__ W,
    const float* __restrict__ a1, const float* __restrict__ a2,
    const float* __restrict__ ab,
    unsigned short* __restrict__ hT, float* __restrict__ s1p,
    float* __restrict__ s2p) {
  __shared__ __align__(16) float Ws[64 * 128];
  __shared__ __align__(16) float Xs[16 * 128];
  const int t = threadIdx.x;
  const int rb = blockIdx.x * 16;
  const int r  = t >> 4;
  const int fg = t & 15;

  {
    int off = t * 8;
    *(f32x4*)(Xs + off)     = *(const f32x4*)(x + (long)rb * 128 + off);
    *(f32x4*)(Xs + off + 4) = *(const f32x4*)(x + (long)rb * 128 + off + 4);
  }

  float acc[8];
#pragma unroll
  for (int j = 0; j < 8; ++j) acc[j] = 0.f;

  for (int half = 0; half < 2; ++half) {
    __syncthreads();
#pragma unroll
    for (int c = 0; c < 8; ++c) {
      int off = c * 1024 + t * 4;
      *(f32x4*)(Ws + off) = *(const f32x4*)(W + half * 8192 + off);
    }
    __syncthreads();
    for (int k = 0; k < 64; ++k) {
      float xv = Xs[r * 128 + half * 64 + k];
      f32x4 w0 = *(const f32x4*)(Ws + k * 128 + fg * 8);
      f32x4 w1 = *(const f32x4*)(Ws + k * 128 + fg * 8 + 4);
#pragma unroll
      for (int j = 0; j < 4; ++j) {
        acc[j]     += xv * w0[j];
        acc[4 + j] += xv * w1[j];
      }
    }
  }

  float p1 = 0.f, p2 = 0.f;
#pragma unroll
  for (int j = 0; j < 8; ++j) {
    p1 += acc[j] * a1[fg * 8 + j];
    p2 += acc[j] * a2[fg * 8 + j];
  }
#pragma unroll
  for (int mask = 1; mask <= 8; mask <<= 1) {
    p1 += __shfl_xor(p1, mask, 64);
    p2 += __shfl_xor(p2, mask, 64);
  }
  if (fg == 0) {
    s1p[rb + r] = LOG2E * (p1 + ab[0]);
    s2p[rb + r] = LOG2E * p2;
  }
#pragma unroll
  for (int j = 0; j < 8; ++j)
    hT[(long)(fg * 8 + j) * 8192 + rb + r] = f2b(acc[j]);
}

// ---------------- kernel 2 v5: A-in-LDS (dbuf), B direct, 1 barrier/iter ----
// grid 512 x 512 thr. Block = 16 rows x 128 f x full K. 8 waves =
// {kh 0,1} x {f-quarter}. All 512 threads produce w non-redundantly
// (8 exp2/thread/iter) into a double-buffered XOR-swizzled A-tile; adj has
// depth-2 register prefetch so the per-iter barrier's vmcnt(0) drain hits
// ~finished loads. B-frags gather straight from L2-resident hT (16 full
// 64B lines per instr), issued post-barrier, consumed same iter.
__global__ __launch_bounds__(512, 4) void k_attn(
    const float* __restrict__ adj, const unsigned short* __restrict__ hT,
    const float* __restrict__ s1p, const float* __restrict__ s2p,
    float* __restrict__ out) {
  __shared__ __align__(16) unsigned short Abuf[2][2][16 * 128]; // [buf][kh][row][k] swizzled, 16 KB
  __shared__ float accC[16 * 128];                              // 8 KB combine
  __shared__ float dens[2][16];

  const int t = threadIdx.x;
  const int i0 = blockIdx.x * 16;
  // w-producer mapping
  const int wh = t >> 8;          // K-half this thread produces w for
  const int wr = (t >> 4) & 15;   // row
  const int wc = t & 15;          // 8-col chunk within the 128-k window
  // MFMA mapping
  const int lane = t & 63;
  const int wv = t >> 6;          // 0..7
  const int kh = wv >> 2;         // K-half this wave MFMAs (== wh)
  const int f0 = (wv & 3) * 32;   // feature quarter
  const int m    = lane & 15;
  const int quad = lane >> 4;

  const float s1v = s1p[i0 + wr];
  const float* adjp = adj + (long)(i0 + wr) * 8192 + wh * 4096 + wc * 8;
  const float* s2pp = s2p + wh * 4096 + wc * 8;
  const unsigned short* hTb = hT + (long)kh * 4096 + quad * 8;
  unsigned short* Aw = &Abuf[0][0][0] + wh * 2048;        // producer side
  const unsigned short* Ar = &Abuf[0][0][0] + kh * 2048;  // consumer side
  const int wslot = (wc ^ (wr & 7)) * 8;                  // producer swizzle

  f32x4 acc0, acc1;
#pragma unroll
  for (int p = 0; p < 4; ++p) { acc0[p] = 0.f; acc1[p] = 0.f; }
  float den = 0.f;

  // ---- prologue: w(0) -> Abuf[0]; prefetch adj/s2 for iter 1 ----
  {
    f32x4 aa = __builtin_nontemporal_load((const f32x4*)(adjp));
    f32x4 ab2 = __builtin_nontemporal_load((const f32x4*)(adjp + 4));
    f32x4 sa = *(const f32x4*)(s2pp);
    f32x4 sb = *(const f32x4*)(s2pp + 4);
    bf16x8 wpk;
#pragma unroll
    for (int j = 0; j < 4; ++j) {
      float tp0 = s1v + sa[j];
      float w0 = aa[j] * EXP2F(fmaxf(tp0, 0.2f * tp0));
      den += w0; wpk[j] = (__bf16)w0;
      float tp1 = s1v + sb[j];
      float w1 = ab2[j] * EXP2F(fmaxf(tp1, 0.2f * tp1));
      den += w1; wpk[4 + j] = (__bf16)w1;
    }
    *(bf16x8*)(Aw + wr * 128 + wslot) = wpk;
  }
  f32x4 caa = __builtin_nontemporal_load((const f32x4*)(adjp + 128));
  f32x4 cab = __builtin_nontemporal_load((const f32x4*)(adjp + 132));
  f32x4 csa = *(const f32x4*)(s2pp + 128);
  f32x4 csb = *(const f32x4*)(s2pp + 132);
  __syncthreads();

  for (int it = 0; it < 32; ++it) {
    // ---- depth-2 adj/s2 prefetch ----
    f32x4 naa, nab, nsa, nsb;
    if (it + 2 < 32) {
      const long o = (long)(it + 2) * 128;
      naa = __builtin_nontemporal_load((const f32x4*)(adjp + o));
      nab = __builtin_nontemporal_load((const f32x4*)(adjp + o + 4));
      nsa = *(const f32x4*)(s2pp + o);
      nsb = *(const f32x4*)(s2pp + o + 4);
    }

    // ---- produce w(it+1) into the other A buffer ----
    if (it + 1 < 32) {
      bf16x8 wpk;
#pragma unroll
      for (int j = 0; j < 4; ++j) {
        float tp0 = s1v + csa[j];
        float w0 = caa[j] * EXP2F(fmaxf(tp0, 0.2f * tp0));
        den += w0; wpk[j] = (__bf16)w0;
        float tp1 = s1v + csb[j];
        float w1 = cab[j] * EXP2F(fmaxf(tp1, 0.2f * tp1));
        den += w1; wpk[4 + j] = (__bf16)w1;
      }
      *(bf16x8*)(Aw + ((it + 1) & 1) * 4096 + wr * 128 + wslot) = wpk;
    }

    // ---- consume: A-frags from Abuf[it&1][kh], B direct from hT ----
    const unsigned short* Ac = Ar + (it & 1) * 4096 + m * 128;
    const unsigned short* hb = hTb + (long)it * 128;
#pragma unroll
    for (int ks = 0; ks < 4; ++ks) {
      int c = ks * 4 + quad;
      bf16x8 af = *(const bf16x8*)(Ac + (c ^ (m & 7)) * 8);
      bf16x8 bv0 = *(const bf16x8*)(hb + (long)(f0 + m) * 8192 + ks * 32);
      bf16x8 bv1 = *(const bf16x8*)(hb + (long)(f0 + 16 + m) * 8192 + ks * 32);
      acc0 = __builtin_amdgcn_mfma_f32_16x16x32_bf16(af, bv0, acc0, 0, 0, 0);
      acc1 = __builtin_amdgcn_mfma_f32_16x16x32_bf16(af, bv1, acc1, 0, 0, 0);
    }
    __syncthreads();   // publish w(it+1); adj(it+2) drain is ~1 iter old

    caa = naa; cab = nab; csa = nsa; csb = nsb;
  }

  // ---- denominator: reduce over wc (lane bits 0..3) -> dens[wh][wr] ----
  den += __shfl_xor(den, 1, 64);
  den += __shfl_xor(den, 2, 64);
  den += __shfl_xor(den, 4, 64);
  den += __shfl_xor(den, 8, 64);
  if (wc == 0) dens[wh][wr] = den;

  // ---- combine K-halves in-block; kh=1 waves publish, kh=0 waves store ----
  if (kh == 1) {
#pragma unroll
    for (int p = 0; p < 4; ++p) {
      int row = quad * 4 + p;    // C layout: col=m, row=quad*4+p [m89]
      accC[row * 128 + f0 + m]      = acc0[p];
      accC[row * 128 + f0 + 16 + m] = acc1[p];
    }
  }
  __syncthreads();
  if (kh == 0) {
#pragma unroll
    for (int p = 0; p < 4; ++p) {
      int row = quad * 4 + p;
      float d = dens[0][row] + dens[1][row];
      float inv = (d != 0.f) ? (1.f / d) : 0.f;
      float v0 = acc0[p] + accC[row * 128 + f0 + m];
      float v1 = acc1[p] + accC[row * 128 + f0 + 16 + m];
      out[(long)(i0 + row) * 128 + f0 + m]      = v0 * inv;
      out[(long)(i0 + row) * 128 + f0 + 16 + m] = v1 * inv;
    }
  }
}

extern "C" void kernel_launch(void* const* d_in, const int* in_sizes, int n_in,
                              void* d_out, int out_size, void* d_ws, size_t ws_size,
                              hipStream_t stream) {
  int ix = 0, iadj = 1, iw = 2, ia1 = 3, ia2 = 4, iab = 5;
  {
    int f128[2] = {-1, -1};
    int tx = -1, tadj = -1, tw = -1, tab = -1, n128 = 0;
    for (int i = 0; i < n_in; ++i) {
      int s = in_sizes[i];
      if (s == 67108864) tadj = i;
      else if (s == 1048576) tx = i;
      else if (s == 16384) tw = i;
      else if (s == 128 && n128 < 2) f128[n128++] = i;
      else if (s == 1) tab = i;
    }
    if (tx >= 0 && tadj >= 0 && tw >= 0 && tab >= 0 && n128 == 2) {
      ix = tx; iadj = tadj; iw = tw; ia1 = f128[0]; ia2 = f128[1]; iab = tab;
    }
  }
  const float* x   = (const float*)d_in[ix];
  const float* adj = (const float*)d_in[iadj];
  const float* W   = (const float*)d_in[iw];
  const float* a1  = (const float*)d_in[ia1];
  const float* a2  = (const float*)d_in[ia2];
  const float* ab  = (const float*)d_in[iab];

  char* ws = (char*)d_ws;
  unsigned short* hT = (unsigned short*)(ws);           // 2 MB  bf16 h^T [128][8192]
  float* s1p = (float*)(ws + 2097152);                  // 32 KB
  float* s2p = (float*)(ws + 2097152 + 32768);          // 32 KB

  k_prep<<<dim3(512), dim3(256), 0, stream>>>(x, W, a1, a2, ab, hT, s1p, s2p);
  k_attn<<<dim3(512), dim3(512), 0, stream>>>(adj, hT, s1p, s2p, (float*)d_out);
}